// Round 4
// baseline (476.862 us; speedup 1.0000x reference)
//
#include <hip/hip_runtime.h>
#include <math.h>

#define SS 2048
#define BB 64
#define DD 1024

typedef float f4v __attribute__((ext_vector_type(4)));

// Kernel A: v[b][d] = sum_e h[b,e] * W[e,d]
// grid (DD/64, BB/4) = (16,16), block 512 = 8 waves (e-split 8).
// unroll 16 -> 8 serial load groups of 16 W-loads each.
__global__ __launch_bounds__(512) void proj_vec_kernel(
    const float* __restrict__ h, const float* __restrict__ W, float* __restrict__ v) {
    int dl = threadIdx.x & 63;
    int eg = threadIdx.x >> 6;
    int d  = blockIdx.x * 64 + dl;
    int b0 = blockIdx.y * 4;
    int e0 = eg * 128;
    const float* h0 = h + (size_t)(b0 + 0) * DD + e0;
    const float* h1 = h + (size_t)(b0 + 1) * DD + e0;
    const float* h2 = h + (size_t)(b0 + 2) * DD + e0;
    const float* h3 = h + (size_t)(b0 + 3) * DD + e0;
    const float* Wp = W + (size_t)e0 * DD + d;
    float a0 = 0.f, a1 = 0.f, a2 = 0.f, a3 = 0.f;
    #pragma unroll 16
    for (int e = 0; e < 128; ++e) {
        float w = Wp[(size_t)e * DD];     // wave: 64 contiguous floats
        a0 = fmaf(h0[e], w, a0);          // h* wave-uniform -> scalar loads
        a1 = fmaf(h1[e], w, a1);
        a2 = fmaf(h2[e], w, a2);
        a3 = fmaf(h3[e], w, a3);
    }
    __shared__ float red[8][4][64];
    red[eg][0][dl] = a0; red[eg][1][dl] = a1;
    red[eg][2][dl] = a2; red[eg][3][dl] = a3;
    __syncthreads();
    if (eg < 4) {   // wave eg reduces b0+eg
        float s = 0.f;
        #pragma unroll
        for (int g = 0; g < 8; ++g) s += red[g][eg][dl];
        v[(size_t)(b0 + eg) * DD + d] = s;
    }
}

// Kernel B (fused): energies[b,s] = enc[s,b,:] . v[b,:], then the block that
// completes the 128th chunk of a given b runs that b's softmax.
// One wave per (b, 16-s chunk). enc loads are nontemporal (read-once stream).
__global__ __launch_bounds__(256) void energy_softmax_kernel(
    const float* __restrict__ enc, const float* __restrict__ vv,
    float* __restrict__ e_ws, int* __restrict__ counters, float* __restrict__ out) {
    __shared__ float part[4][16][65];    // [wave][row][lane], pad -> 2-way max (free)
    __shared__ float red[256];
    __shared__ int   myb[4];
    int tid  = threadIdx.x;
    int w    = tid >> 6;
    int lane = tid & 63;
    int wid  = blockIdx.x * 4 + w;
    int b  = wid & (BB - 1);
    int sc = wid >> 6;                   // 0..127
    const f4v* vr = (const f4v*)(vv + (size_t)b * DD);
    f4v w0 = vr[lane];
    f4v w1 = vr[lane + 64];
    f4v w2 = vr[lane + 128];
    f4v w3 = vr[lane + 192];
    int s0 = sc * 16;
    #pragma unroll 2
    for (int i = 0; i < 16; ++i) {
        const f4v* r0 = (const f4v*)(enc + ((size_t)(s0 + i) * BB + b) * DD);
        f4v a0 = __builtin_nontemporal_load(r0 + lane);
        f4v a1 = __builtin_nontemporal_load(r0 + lane + 64);
        f4v a2 = __builtin_nontemporal_load(r0 + lane + 128);
        f4v a3 = __builtin_nontemporal_load(r0 + lane + 192);
        float p = a0[0]*w0[0] + a0[1]*w0[1] + a0[2]*w0[2] + a0[3]*w0[3]
                + a1[0]*w1[0] + a1[1]*w1[1] + a1[2]*w1[2] + a1[3]*w1[3]
                + a2[0]*w2[0] + a2[1]*w2[1] + a2[2]*w2[2] + a2[3]*w2[3]
                + a3[0]*w3[0] + a3[1]*w3[1] + a3[2]*w3[2] + a3[3]*w3[3];
        part[w][i][lane] = p;
    }
    __syncthreads();
    // Epilogue: 4 lanes per row; each sums 16 LDS entries, then 2 shfls.
    int r  = lane >> 2;
    int qd = lane & 3;
    float sum = 0.f;
    #pragma unroll
    for (int k = 0; k < 16; ++k) sum += part[w][r][qd * 16 + k];
    sum += __shfl_xor(sum, 1, 64);
    sum += __shfl_xor(sum, 2, 64);
    if (qd == 0) e_ws[b * SS + s0 + r] = sum;

    // Release our energy writes, then signal completion per b.
    __threadfence();
    __syncthreads();
    if (tid < 4) {
        int bb  = (blockIdx.x * 4 + tid) & (BB - 1);
        int old = atomicAdd(&counters[bb], 1);
        myb[tid] = (old == 127) ? bb : -1;   // last of 128 chunks for bb
    }
    __syncthreads();
    #pragma unroll 1
    for (int j = 0; j < 4; ++j) {
        int bb = myb[j];
        if (bb < 0) continue;
        __threadfence();                 // acquire: see all chunks of bb
        float vals[8];
        float m = -INFINITY;
        #pragma unroll
        for (int k = 0; k < 8; ++k) {
            vals[k] = e_ws[bb * SS + tid + 256 * k];
            m = fmaxf(m, vals[k]);
        }
        red[tid] = m;
        __syncthreads();
        for (int off = 128; off > 0; off >>= 1) {
            if (tid < off) red[tid] = fmaxf(red[tid], red[tid + off]);
            __syncthreads();
        }
        m = red[0];
        __syncthreads();
        float s = 0.f;
        #pragma unroll
        for (int k = 0; k < 8; ++k) {
            vals[k] = expf(vals[k] - m);
            s += vals[k];
        }
        red[tid] = s;
        __syncthreads();
        for (int off = 128; off > 0; off >>= 1) {
            if (tid < off) red[tid] += red[tid + off];
            __syncthreads();
        }
        float inv = 1.0f / red[0];
        #pragma unroll
        for (int k = 0; k < 8; ++k)
            out[bb * SS + tid + 256 * k] = vals[k] * inv;
        __syncthreads();
    }
}

extern "C" void kernel_launch(void* const* d_in, const int* in_sizes, int n_in,
                              void* d_out, int out_size, void* d_ws, size_t ws_size,
                              hipStream_t stream) {
    const float* hidden = (const float*)d_in[0];   // [1,B,D]
    const float* enc    = (const float*)d_in[1];   // [S,B,D]
    const float* W      = (const float*)d_in[2];   // [D,D]
    // d_in[3] = b_attn: constant per-b shift -> cancels in softmax, unused.
    float* out = (float*)d_out;                    // [B,1,S]

    float* v        = (float*)d_ws;                                     // 256 KB
    float* e_ws     = (float*)((char*)d_ws + BB * DD * sizeof(float));  // 512 KB
    int*   counters = (int*)((char*)d_ws + (BB * DD + BB * SS) * sizeof(float));

    hipMemsetAsync(counters, 0, BB * sizeof(int), stream);  // capture-safe memset node
    dim3 gA(DD / 64, BB / 4);
    proj_vec_kernel<<<gA, 512, 0, stream>>>(hidden, W, v);
    energy_softmax_kernel<<<2048, 256, 0, stream>>>(enc, v, e_ws, counters, out);
}

// Round 5
// 117.903 us; speedup vs baseline: 4.0445x; 4.0445x over previous
//
#include <hip/hip_runtime.h>
#include <math.h>

#define SS 2048
#define BB 64
#define DD 1024

// Kernel A: v[b][d] = sum_e h[b,e] * W[e,d]
// grid (DD/64, BB/4) = (16,16), block 512 = 8 waves (e-split 8).
__global__ __launch_bounds__(512) void proj_vec_kernel(
    const float* __restrict__ h, const float* __restrict__ W, float* __restrict__ v) {
    int dl = threadIdx.x & 63;
    int eg = threadIdx.x >> 6;
    int d  = blockIdx.x * 64 + dl;
    int b0 = blockIdx.y * 4;
    int e0 = eg * 128;
    const float* h0 = h + (size_t)(b0 + 0) * DD + e0;
    const float* h1 = h + (size_t)(b0 + 1) * DD + e0;
    const float* h2 = h + (size_t)(b0 + 2) * DD + e0;
    const float* h3 = h + (size_t)(b0 + 3) * DD + e0;
    const float* Wp = W + (size_t)e0 * DD + d;
    float a0 = 0.f, a1 = 0.f, a2 = 0.f, a3 = 0.f;
    #pragma unroll 16
    for (int e = 0; e < 128; ++e) {
        float w = Wp[(size_t)e * DD];     // wave: 64 contiguous floats
        a0 = fmaf(h0[e], w, a0);          // h* wave-uniform -> scalar loads
        a1 = fmaf(h1[e], w, a1);
        a2 = fmaf(h2[e], w, a2);
        a3 = fmaf(h3[e], w, a3);
    }
    __shared__ float red[8][4][64];
    red[eg][0][dl] = a0; red[eg][1][dl] = a1;
    red[eg][2][dl] = a2; red[eg][3][dl] = a3;
    __syncthreads();
    if (eg < 4) {   // wave eg reduces b0+eg
        float s = 0.f;
        #pragma unroll
        for (int g = 0; g < 8; ++g) s += red[g][eg][dl];
        v[(size_t)(b0 + eg) * DD + d] = s;
    }
}

// Kernel B: energies[b,s] = enc[s,b,:] . v[b,:]
// One wave per (b, 16-s chunk); v-row in 16 VGPRs. Two rows per iteration:
// 8 float4 loads issued before any FMA (8 KB in flight per wave). No
// cross-lane ops in the loop; per-lane partials -> LDS; epilogue reduces.
__global__ __launch_bounds__(256) void energy_kernel(
    const float* __restrict__ enc, const float* __restrict__ vv, float* __restrict__ e_out) {
    __shared__ float part[4][16][65];    // [wave][row][lane], pad -> 2-way max (free)
    int tid  = threadIdx.x;
    int w    = tid >> 6;
    int lane = tid & 63;
    int wid  = blockIdx.x * 4 + w;
    int b  = wid & (BB - 1);
    int sc = wid >> 6;                   // 0..127
    const float4* vr = (const float4*)(vv + (size_t)b * DD);
    float4 w0 = vr[lane];
    float4 w1 = vr[lane + 64];
    float4 w2 = vr[lane + 128];
    float4 w3 = vr[lane + 192];
    int s0 = sc * 16;
    #pragma unroll 1
    for (int i = 0; i < 16; i += 2) {
        const float4* r0 = (const float4*)(enc + ((size_t)(s0 + i)     * BB + b) * DD);
        const float4* r1 = (const float4*)(enc + ((size_t)(s0 + i + 1) * BB + b) * DD);
        float4 a0 = r0[lane];
        float4 a1 = r0[lane + 64];
        float4 a2 = r0[lane + 128];
        float4 a3 = r0[lane + 192];
        float4 c0 = r1[lane];
        float4 c1 = r1[lane + 64];
        float4 c2 = r1[lane + 128];
        float4 c3 = r1[lane + 192];
        float p = a0.x*w0.x + a0.y*w0.y + a0.z*w0.z + a0.w*w0.w
                + a1.x*w1.x + a1.y*w1.y + a1.z*w1.z + a1.w*w1.w
                + a2.x*w2.x + a2.y*w2.y + a2.z*w2.z + a2.w*w2.w
                + a3.x*w3.x + a3.y*w3.y + a3.z*w3.z + a3.w*w3.w;
        float q = c0.x*w0.x + c0.y*w0.y + c0.z*w0.z + c0.w*w0.w
                + c1.x*w1.x + c1.y*w1.y + c1.z*w1.z + c1.w*w1.w
                + c2.x*w2.x + c2.y*w2.y + c2.z*w2.z + c2.w*w2.w
                + c3.x*w3.x + c3.y*w3.y + c3.z*w3.z + c3.w*w3.w;
        part[w][i][lane]     = p;
        part[w][i + 1][lane] = q;
    }
    __syncthreads();
    // Epilogue: 4 lanes per row; each sums 16 LDS entries, then 2 shfls.
    int r  = lane >> 2;                  // row 0..15
    int qd = lane & 3;                   // quarter
    float sum = 0.f;
    #pragma unroll
    for (int k = 0; k < 16; ++k) sum += part[w][r][qd * 16 + k];
    sum += __shfl_xor(sum, 1, 64);
    sum += __shfl_xor(sum, 2, 64);
    if (qd == 0) e_out[b * SS + s0 + r] = sum;
}

// Kernel C: softmax over s per b. 64 blocks x 256 threads, 8 elems/thread.
__global__ __launch_bounds__(256) void softmax_kernel(
    const float* __restrict__ e_in, float* __restrict__ out) {
    int b   = blockIdx.x;
    int tid = threadIdx.x;
    __shared__ float red[256];
    float vals[8];
    float m = -INFINITY;
    #pragma unroll
    for (int k = 0; k < 8; ++k) {
        vals[k] = e_in[b * SS + tid + 256 * k];
        m = fmaxf(m, vals[k]);
    }
    red[tid] = m;
    __syncthreads();
    for (int off = 128; off > 0; off >>= 1) {
        if (tid < off) red[tid] = fmaxf(red[tid], red[tid + off]);
        __syncthreads();
    }
    m = red[0];
    __syncthreads();
    float sum = 0.f;
    #pragma unroll
    for (int k = 0; k < 8; ++k) {
        vals[k] = expf(vals[k] - m);
        sum += vals[k];
    }
    red[tid] = sum;
    __syncthreads();
    for (int off = 128; off > 0; off >>= 1) {
        if (tid < off) red[tid] += red[tid + off];
        __syncthreads();
    }
    float inv = 1.0f / red[0];
    #pragma unroll
    for (int k = 0; k < 8; ++k)
        out[b * SS + tid + 256 * k] = vals[k] * inv;
}

extern "C" void kernel_launch(void* const* d_in, const int* in_sizes, int n_in,
                              void* d_out, int out_size, void* d_ws, size_t ws_size,
                              hipStream_t stream) {
    const float* hidden = (const float*)d_in[0];   // [1,B,D]
    const float* enc    = (const float*)d_in[1];   // [S,B,D]
    const float* W      = (const float*)d_in[2];   // [D,D]
    // d_in[3] = b_attn: constant per-b shift -> cancels in softmax, unused.
    float* out = (float*)d_out;                    // [B,1,S]

    float* v    = (float*)d_ws;                                      // B*D = 256 KB
    float* e_ws = (float*)((char*)d_ws + BB * DD * sizeof(float));   // B*S = 512 KB

    dim3 gA(DD / 64, BB / 4);
    proj_vec_kernel<<<gA, 512, 0, stream>>>(hidden, W, v);
    energy_kernel<<<2048, 256, 0, stream>>>(enc, v, e_ws);
    softmax_kernel<<<BB, 256, 0, stream>>>(e_ws, out);
}